// Round 12
// baseline (178.816 us; speedup 1.0000x reference)
//
#include <hip/hip_runtime.h>
#include <stdint.h>

typedef unsigned long long u64;

#define N 8192
#define NW 128            // 64-bit words per mask row
#define MAX_OUT 256
#define MASK_BYTES ((size_t)N * NW * 8)   // 8 MiB

// ws layout:
//   [0, 8MB)    maskT u64[NW][N]  (column-major: maskT[w*N + i])
//   +8MB        order  int[N]     32 KB
//   +32KB       s_s    float[N]   32 KB
//   +64KB       bbox   float4[N] 128 KB
//   +192KB      area   float[N]   32 KB
//   +224KB      nvalid int
// No init needed anywhere (rank is a permutation; maskT garbage only in
// never-consumed positions; nvalid written each launch).

// ========== Kernel 1: fused rank + scatter + nvalid (no atomics, no init) ====
__global__ __launch_bounds__(1024)
void rank_fused_kernel(const float* __restrict__ score, const float* __restrict__ box,
                       int* __restrict__ order, float* __restrict__ s_s,
                       float4* __restrict__ bbox, float* __restrict__ area,
                       int* __restrict__ nvalid) {
    __shared__ uint32_t ksc[N];        // 32 KB: all score bit-patterns
    __shared__ int psum[32][33];       // +1 pad
    __shared__ int vpart[16];
    const int tid = threadIdx.x;

    const float4* s4 = (const float4*)score;
    float4 a = s4[tid * 2], b = s4[tid * 2 + 1];
    ksc[tid * 8 + 0] = __float_as_uint(a.x);
    ksc[tid * 8 + 1] = __float_as_uint(a.y);
    ksc[tid * 8 + 2] = __float_as_uint(a.z);
    ksc[tid * 8 + 3] = __float_as_uint(a.w);
    ksc[tid * 8 + 4] = __float_as_uint(b.x);
    ksc[tid * 8 + 5] = __float_as_uint(b.y);
    ksc[tid * 8 + 6] = __float_as_uint(b.z);
    ksc[tid * 8 + 7] = __float_as_uint(b.w);
    int c = (a.x >= 0.3f) + (a.y >= 0.3f) + (a.z >= 0.3f) + (a.w >= 0.3f)
          + (b.x >= 0.3f) + (b.y >= 0.3f) + (b.z >= 0.3f) + (b.w >= 0.3f);
    for (int off = 32; off; off >>= 1) c += __shfl_down(c, off);
    if ((tid & 63) == 0) vpart[tid >> 6] = c;
    __syncthreads();
    if (blockIdx.x == 0 && tid == 0) {
        int t = 0;
        #pragma unroll
        for (int w = 0; w < 16; ++w) t += vpart[w];
        *nvalid = t;
    }

    const int i_local = tid & 31;
    const int jg = tid >> 5;
    const int ibase = blockIdx.x * 32;
    const uint32_t si = ksc[ibase + i_local];
    const int i = ibase + i_local;
    int cnt = 0;
    const int j0 = jg * 256;
    #pragma unroll 8
    for (int t = 0; t < 256; ++t) {
        const int j = j0 + t;
        const uint32_t sj = ksc[j];
        cnt += (sj > si || (sj == si && j < i)) ? 1 : 0;
    }
    psum[i_local][jg] = cnt;
    __syncthreads();

    if (tid < 32) {
        int r = 0;
        #pragma unroll
        for (int k = 0; k < 32; ++k) r += psum[tid][k];
        const int ii = ibase + tid;
        order[r] = ii;
        s_s[r] = score[ii];
        float4 cb = ((const float4*)box)[ii * 4];   // first 4 of 16: cx,cy,w,h
        float hw = cb.z * 0.5f, hh = cb.w * 0.5f;
        float x0 = cb.x - hw, y0 = cb.y - hh, x1 = cb.x + hw, y1 = cb.y + hh;
        bbox[r] = make_float4(x0, y0, x1, y1);
        area[r] = (x1 - x0) * (y1 - y0);            // replicate ref: area from xyxy
    }
}

// ========== Kernel 2: suppression bitmask, column-major, div-free fast path ==
__global__ __launch_bounds__(256)
void mask_kernel(const float4* __restrict__ bbox, const float* __restrict__ area,
                 const int* __restrict__ nvalid_p, u64* __restrict__ maskT) {
    const int w = blockIdx.x;
    if (w < (int)(blockIdx.y << 2)) return;          // whole block below diagonal
    const int nv = *nvalid_p;
    if ((int)(blockIdx.y * 256) >= nv) return;
    __shared__ float4 jb[64];
    __shared__ float  ja[64];
    if (threadIdx.x < 64) {
        jb[threadIdx.x] = bbox[w * 64 + threadIdx.x];
        ja[threadIdx.x] = area[w * 64 + threadIdx.x];
    }
    __syncthreads();
    const int i = blockIdx.y * 256 + threadIdx.x;
    if (i >= nv) return;
    if (w < (i >> 6)) return;
    float4 aa4 = bbox[i];
    float  aa = area[i];
    u64 bits = 0, fb = 0;
    #pragma unroll 8
    for (int jj = 0; jj < 64; ++jj) {
        float4 b = jb[jj];
        float lx = fmaxf(aa4.x, b.x), ly = fmaxf(aa4.y, b.y);
        float rx = fminf(aa4.z, b.z), ry = fminf(aa4.w, b.w);
        float ww = fmaxf(rx - lx, 0.0f), hh = fmaxf(ry - ly, 0.0f);
        float inter = ww * hh;
        float denom = ((aa + ja[jj]) - inter) + 1e-9f;  // exact ref op order
        float d = fmaf(-0.3f, denom, inter);            // sign decides iou>0.3
        bits |= ((u64)(d > 0.0f)) << jj;
        fb   |= ((u64)(fabsf(d) <= 1e-5f * denom)) << jj;
    }
    if (fb) {   // rare exact-divide fixup (margin 1e-5 >> ulp(0.3f)~3e-8)
        while (fb) {
            int jj = (int)__builtin_ctzll(fb); fb &= fb - 1;
            float4 b = jb[jj];
            float lx = fmaxf(aa4.x, b.x), ly = fmaxf(aa4.y, b.y);
            float rx = fminf(aa4.z, b.z), ry = fminf(aa4.w, b.w);
            float ww = fmaxf(rx - lx, 0.0f), hh = fmaxf(ry - ly, 0.0f);
            float inter = ww * hh;
            float denom = ((aa + ja[jj]) - inter) + 1e-9f;
            float iou = inter / denom;                   // IEEE div, matches np
            bits = (bits & ~(1ull << jj)) | (((u64)(iou > 0.3f)) << jj);
        }
    }
    maskT[(size_t)w * N + i] = bits;                     // coalesced
}

// ========== Kernel 3: serial greedy — lane-owned remv (3rd attempt) ==========
// Lane l owns suppression words for blocks l (remv0) and 64+l (remv1);
// nblk <= 128 so the window covers all blocks. Per block b:
//   rw = RL64(remv, b) | rsup            — 2 readlanes; NO DPP reduce/gathers
//   remv covers kept <= b-2 (deferred row-word loads: when r kept at block q,
//     lane l loads maskT[l][r], maskT[64+l][r]; 4 unconditional slots with
//     default addresses, scalar-count-masked at the b+2 merge)
//   rsup covers kept at b-1 (per-kept RL64 broadcast of the in-pipe spec word
//     s1 = maskT[b+1][rows of b]) — only ONE generation needed at 2-deep.
//   in-block: ballot symmetry on the diagonal word (col), unchanged.
// Lower-triangle garbage words land only in already-consumed remv words
// (R2/R6-validated argument; both passed correctness).
// Fixes vs R2/R6: flat named u64 state + __launch_bounds__(64,1) — R10 proved
// the allocator grants 92+ VGPR under (64,1); R2/R6 spilled without it.
// Diagnostic pre-commit: VGPR 75-110 expected; ~40 => spilled => revert.

#define RL64(v, l) ( ((u64)(unsigned)__builtin_amdgcn_readlane((int)(unsigned)((v) >> 32), (l)) << 32) \
                   |  (u64)(unsigned)__builtin_amdgcn_readlane((int)(unsigned)(v), (l)) )

#define NMS_STEP(B, PCOL, PS1, D0,D1,D2,D3,D4,D5,D6,D7, DCNT) do {            \
    const int b_ = (B);                                                        \
    /* 1. merge deferred set (issued at b-2; count-masked, scalar selects) */  \
    {                                                                          \
        const int c_ = DCNT;                                                   \
        remv0 |= (c_ > 0 ? D0 : 0) | (c_ > 1 ? D2 : 0)                         \
               | (c_ > 2 ? D4 : 0) | (c_ > 3 ? D6 : 0);                        \
        remv1 |= (c_ > 0 ? D1 : 0) | (c_ > 1 ? D3 : 0)                         \
               | (c_ > 2 ? D5 : 0) | (c_ > 3 ? D7 : 0);                        \
    }                                                                          \
    /* 2. suppression word: 2 readlanes + rsup */                              \
    u64 sel_ = (b_ < 64) ? remv0 : remv1;                                      \
    u64 rw_ = RL64(sel_, b_ & 63) | rsup;                                      \
    /* 3. consume pipe (tail-masked at consume, never at issue) */             \
    u64 col_ = PCOL;                                                           \
    u64 s1v_ = (b_ + 1 < nblk) ? PS1 : 0;                                      \
    /* 4. reissue col/spec for b+2 (unconditional, clamped addresses) */       \
    {                                                                          \
        const int nb1_ = nblk - 1;                                             \
        const int bc_ = (b_ + 2 < nb1_) ? (b_ + 2) : nb1_;                     \
        const int w1_ = (b_ + 3 < nb1_) ? (b_ + 3) : nb1_;                     \
        const int row_ = (bc_ << 6) + lane;                                    \
        PCOL = maskT[(size_t)bc_ * N + row_];                                  \
        PS1  = maskT[(size_t)w1_ * N + row_];                                  \
    }                                                                          \
    /* 5. resolve */                                                           \
    const int base_ = b_ << 6;                                                 \
    const int rem_ = nv - base_;                                               \
    u64 validm_ = (rem_ >= 64) ? ~0ull : ((1ull << rem_) - 1ull);              \
    u64 todo_ = validm_ & ~rw_;                                                \
    u64 km_ = 0;                                                               \
    while (todo_) {                                                            \
        int l_ = (int)__builtin_ctzll(todo_);                                  \
        u64 rowl_ = __ballot(((col_ >> l_) & 1ull) != 0);                      \
        const int pos_ = base_ + l_;                                           \
        const bool own_ = (lane == (kcount & 63));                             \
        const int slot_ = kcount >> 6;                                         \
        kp0 = (own_ && slot_ == 0) ? pos_ : kp0;                               \
        kp1 = (own_ && slot_ == 1) ? pos_ : kp1;                               \
        kp2 = (own_ && slot_ == 2) ? pos_ : kp2;                               \
        kp3 = (own_ && slot_ == 3) ? pos_ : kp3;                               \
        km_ |= (1ull << l_);                                                   \
        kcount++;                                                              \
        /* diagonal bit of rowl_ not guaranteed for degenerate tiny boxes */   \
        todo_ &= ~(rowl_ | (1ull << l_));                                      \
        if (kcount >= MAX_OUT) break;                                          \
    }                                                                          \
    /* 6. rsup for block b+1: per-kept broadcast of spec word (kept rows<nv) */\
    u64 add1_ = 0, t_ = km_;                                                   \
    while (t_) { int l_ = (int)__builtin_ctzll(t_); t_ &= t_ - 1;              \
                 add1_ |= RL64(s1v_, l_); }                                    \
    rsup = add1_;                                                              \
    /* 7. deferred row-word loads (merged at b+2): 4 unconditional slots */    \
    {                                                                          \
        u64 t2_ = km_;                                                         \
        int r0_ = base_, r1_ = base_, r2_ = base_, r3_ = base_, c2_ = 0;       \
        if (t2_) { r0_ = base_ + (int)__builtin_ctzll(t2_); t2_ &= t2_ - 1; c2_ = 1; } \
        if (t2_) { r1_ = base_ + (int)__builtin_ctzll(t2_); t2_ &= t2_ - 1; c2_ = 2; } \
        if (t2_) { r2_ = base_ + (int)__builtin_ctzll(t2_); t2_ &= t2_ - 1; c2_ = 3; } \
        if (t2_) { r3_ = base_ + (int)__builtin_ctzll(t2_); t2_ &= t2_ - 1; c2_ = 4; } \
        D0 = maskT[woffL + r0_]; D1 = maskT[woffH + r0_];                      \
        D2 = maskT[woffL + r1_]; D3 = maskT[woffH + r1_];                      \
        D4 = maskT[woffL + r2_]; D5 = maskT[woffH + r2_];                      \
        D6 = maskT[woffL + r3_]; D7 = maskT[woffH + r3_];                      \
        DCNT = c2_;                                                            \
        /* rare overflow (>4 kept/block): synchronous merge, correct */        \
        while (t2_) { int l_ = (int)__builtin_ctzll(t2_); t2_ &= t2_ - 1;      \
                      const int r_ = base_ + l_;                               \
                      remv0 |= maskT[woffL + r_]; remv1 |= maskT[woffH + r_]; }\
    }                                                                          \
    run = (kcount < MAX_OUT);                                                  \
} while (0)

__global__ __launch_bounds__(64, 1)
void nms_kernel(const u64* __restrict__ maskT, const float* __restrict__ s_s,
                const int* __restrict__ order, const float* __restrict__ box,
                const int* __restrict__ nvalid_p, float* __restrict__ out) {
    const int lane = threadIdx.x;
    const int nv = *nvalid_p;
    const int nblk = (nv + 63) >> 6;
    int kcount = 0;
    int kp0 = 0, kp1 = 0, kp2 = 0, kp3 = 0;   // kept idx slots lane, 64+l, 128+l, 192+l
    u64 remv0 = 0, remv1 = 0, rsup = 0;
    const size_t woffL = (size_t)lane * N;
    const size_t woffH = (size_t)(64 + lane) * N;

    // pipes (col + spec1 per parity) and deferred sets (8 u64 + count each)
    u64 Acol = 0, As1 = 0, Bcol = 0, Bs1 = 0;
    u64 da0=0,da1=0,da2=0,da3=0,da4=0,da5=0,da6=0,da7=0; int dcntA = 0;
    u64 db0=0,db1=0,db2=0,db3=0,db4=0,db5=0,db6=0,db7=0; int dcntB = 0;

    // prologue: prime pipes for blocks 0 and 1 (clamped; consume-side masks)
    if (nblk > 0) {
        const int nb1 = nblk - 1;
        const int w1 = (1 < nb1) ? 1 : nb1;
        Acol = maskT[lane];
        As1  = maskT[(size_t)w1 * N + lane];
        if (nblk > 1) {
            const int w2 = (2 < nb1) ? 2 : nb1;
            const int row = 64 + lane;
            Bcol = maskT[(size_t)1 * N + row];
            Bs1  = maskT[(size_t)w2 * N + row];
        }
    }

    bool run = true;
    for (int b = 0; run && b < nblk; b += 2) {
        NMS_STEP(b, Acol, As1, da0,da1,da2,da3,da4,da5,da6,da7, dcntA);
        if (run && b + 1 < nblk)
            NMS_STEP(b + 1, Bcol, Bs1, db0,db1,db2,db3,db4,db5,db6,db7, dcntB);
    }

    // outputs: [score 256][box 256*16][valid 256], all float32
    float* out_score = out;
    float* out_box   = out + MAX_OUT;
    float* out_valid = out + MAX_OUT + MAX_OUT * 16;
    const float4* box4 = (const float4*)box;
    float4* ob4 = (float4*)out_box;
    #define EMIT_SLOT(Q, KP) do {                                              \
        const int t = lane + 64 * (Q);                                         \
        if (t < kcount) {                                                      \
            int p = (KP);                                                      \
            out_score[t] = s_s[p];                                             \
            out_valid[t] = 1.0f;                                               \
            int oi = order[p];                                                 \
            _Pragma("unroll")                                                  \
            for (int q = 0; q < 4; ++q) ob4[t * 4 + q] = box4[oi * 4 + q];     \
        } else {                                                               \
            out_score[t] = 0.0f;                                               \
            out_valid[t] = 0.0f;                                               \
            float4 z = make_float4(0.f, 0.f, 0.f, 0.f);                        \
            _Pragma("unroll")                                                  \
            for (int q = 0; q < 4; ++q) ob4[t * 4 + q] = z;                    \
        }                                                                      \
    } while (0)
    EMIT_SLOT(0, kp0);
    EMIT_SLOT(1, kp1);
    EMIT_SLOT(2, kp2);
    EMIT_SLOT(3, kp3);
    #undef EMIT_SLOT
}

extern "C" void kernel_launch(void* const* d_in, const int* in_sizes, int n_in,
                              void* d_out, int out_size, void* d_ws, size_t ws_size,
                              hipStream_t stream) {
    const float* score = (const float*)d_in[0];   // (8192,1) f32
    const float* box   = (const float*)d_in[1];   // (8192,16) f32
    char* ws = (char*)d_ws;
    u64*    maskT  = (u64*)ws;
    int*    order  = (int*)   (ws + MASK_BYTES);
    float*  s_s    = (float*) (ws + MASK_BYTES + 32768);
    float4* bbox   = (float4*)(ws + MASK_BYTES + 65536);
    float*  area   = (float*) (ws + MASK_BYTES + 65536 + 131072);
    int*    nvalid = (int*)   (ws + MASK_BYTES + 65536 + 131072 + 32768);

    rank_fused_kernel<<<256, 1024, 0, stream>>>(score, box, order, s_s, bbox, area, nvalid);
    mask_kernel<<<dim3(128, 32), 256, 0, stream>>>(bbox, area, nvalid, maskT);
    nms_kernel<<<1, 64, 0, stream>>>(maskT, s_s, order, box, nvalid, (float*)d_out);
}

// Round 13
// 123.659 us; speedup vs baseline: 1.4460x; 1.4460x over previous
//
#include <hip/hip_runtime.h>
#include <stdint.h>

typedef unsigned long long u64;

#define N 8192
#define NW 128            // 64-bit words per mask row
#define MAX_OUT 256
#define MASK_BYTES ((size_t)N * NW * 8)   // 8 MiB

// ws layout:
//   [0, 8MB)    maskT u64[NW][N]  (column-major: maskT[w*N + i])
//   +8MB        order  int[N]     32 KB
//   +32KB       s_s    float[N]   32 KB
//   +64KB       bbox   float4[N] 128 KB
//   +192KB      area   float[N]   32 KB
//   +224KB      nvalid int
// No init needed anywhere (rank is a permutation; maskT garbage only in
// never-consumed positions; nvalid written each launch).

// ========== Kernel 1: fused rank + scatter + nvalid (no atomics, no init) ====
// 256 blocks x 1024 threads. Every block stages all 8192 score-bit keys in
// LDS, ranks its 32 rows (32-way j-split within block, LDS psum reduce),
// then threads 0..31 scatter order/s_s/bbox/area. Stable desc sort:
// rank(i) = #{j: s_j > s_i} + #{j < i: s_j == s_i}.
__global__ __launch_bounds__(1024)
void rank_fused_kernel(const float* __restrict__ score, const float* __restrict__ box,
                       int* __restrict__ order, float* __restrict__ s_s,
                       float4* __restrict__ bbox, float* __restrict__ area,
                       int* __restrict__ nvalid) {
    __shared__ uint32_t ksc[N];        // 32 KB: all score bit-patterns
    __shared__ int psum[32][33];       // +1 pad
    __shared__ int vpart[16];
    const int tid = threadIdx.x;

    const float4* s4 = (const float4*)score;
    float4 a = s4[tid * 2], b = s4[tid * 2 + 1];
    ksc[tid * 8 + 0] = __float_as_uint(a.x);
    ksc[tid * 8 + 1] = __float_as_uint(a.y);
    ksc[tid * 8 + 2] = __float_as_uint(a.z);
    ksc[tid * 8 + 3] = __float_as_uint(a.w);
    ksc[tid * 8 + 4] = __float_as_uint(b.x);
    ksc[tid * 8 + 5] = __float_as_uint(b.y);
    ksc[tid * 8 + 6] = __float_as_uint(b.z);
    ksc[tid * 8 + 7] = __float_as_uint(b.w);
    int c = (a.x >= 0.3f) + (a.y >= 0.3f) + (a.z >= 0.3f) + (a.w >= 0.3f)
          + (b.x >= 0.3f) + (b.y >= 0.3f) + (b.z >= 0.3f) + (b.w >= 0.3f);
    for (int off = 32; off; off >>= 1) c += __shfl_down(c, off);
    if ((tid & 63) == 0) vpart[tid >> 6] = c;
    __syncthreads();
    if (blockIdx.x == 0 && tid == 0) {
        int t = 0;
        #pragma unroll
        for (int w = 0; w < 16; ++w) t += vpart[w];
        *nvalid = t;
    }

    const int i_local = tid & 31;
    const int jg = tid >> 5;
    const int ibase = blockIdx.x * 32;
    const uint32_t si = ksc[ibase + i_local];
    const int i = ibase + i_local;
    int cnt = 0;
    const int j0 = jg * 256;
    #pragma unroll 8
    for (int t = 0; t < 256; ++t) {
        const int j = j0 + t;
        const uint32_t sj = ksc[j];
        cnt += (sj > si || (sj == si && j < i)) ? 1 : 0;
    }
    psum[i_local][jg] = cnt;
    __syncthreads();

    if (tid < 32) {
        int r = 0;
        #pragma unroll
        for (int k = 0; k < 32; ++k) r += psum[tid][k];
        const int ii = ibase + tid;
        order[r] = ii;
        s_s[r] = score[ii];
        float4 cb = ((const float4*)box)[ii * 4];   // first 4 of 16: cx,cy,w,h
        float hw = cb.z * 0.5f, hh = cb.w * 0.5f;
        float x0 = cb.x - hw, y0 = cb.y - hh, x1 = cb.x + hw, y1 = cb.y + hh;
        bbox[r] = make_float4(x0, y0, x1, y1);
        area[r] = (x1 - x0) * (y1 - y0);            // replicate ref: area from xyxy
    }
}

// ========== Kernel 2: suppression bitmask, column-major, div-free fast path ==
// maskT[w*N + i]: coalesced 8B stores (consecutive i per wave).
// iou > 0.3f decided by d = fma(-0.3, denom, inter) with 1e-5 relative guard;
// |d| <= 1e-5*denom redone with the exact IEEE divide -> bit-identical.
__global__ __launch_bounds__(256)
void mask_kernel(const float4* __restrict__ bbox, const float* __restrict__ area,
                 const int* __restrict__ nvalid_p, u64* __restrict__ maskT) {
    const int w = blockIdx.x;
    if (w < (int)(blockIdx.y << 2)) return;          // whole block below diagonal
    const int nv = *nvalid_p;
    if ((int)(blockIdx.y * 256) >= nv) return;
    __shared__ float4 jb[64];
    __shared__ float  ja[64];
    if (threadIdx.x < 64) {
        jb[threadIdx.x] = bbox[w * 64 + threadIdx.x];
        ja[threadIdx.x] = area[w * 64 + threadIdx.x];
    }
    __syncthreads();
    const int i = blockIdx.y * 256 + threadIdx.x;
    if (i >= nv) return;
    if (w < (i >> 6)) return;
    float4 aa4 = bbox[i];
    float  aa = area[i];
    u64 bits = 0, fb = 0;
    #pragma unroll 8
    for (int jj = 0; jj < 64; ++jj) {
        float4 b = jb[jj];
        float lx = fmaxf(aa4.x, b.x), ly = fmaxf(aa4.y, b.y);
        float rx = fminf(aa4.z, b.z), ry = fminf(aa4.w, b.w);
        float ww = fmaxf(rx - lx, 0.0f), hh = fmaxf(ry - ly, 0.0f);
        float inter = ww * hh;
        float denom = ((aa + ja[jj]) - inter) + 1e-9f;  // exact ref op order
        float d = fmaf(-0.3f, denom, inter);            // sign decides iou>0.3
        bits |= ((u64)(d > 0.0f)) << jj;
        fb   |= ((u64)(fabsf(d) <= 1e-5f * denom)) << jj;
    }
    if (fb) {   // rare exact-divide fixup (margin 1e-5 >> ulp(0.3f)~3e-8)
        while (fb) {
            int jj = (int)__builtin_ctzll(fb); fb &= fb - 1;
            float4 b = jb[jj];
            float lx = fmaxf(aa4.x, b.x), ly = fmaxf(aa4.y, b.y);
            float rx = fminf(aa4.z, b.z), ry = fminf(aa4.w, b.w);
            float ww = fmaxf(rx - lx, 0.0f), hh = fmaxf(ry - ly, 0.0f);
            float inter = ww * hh;
            float denom = ((aa + ja[jj]) - inter) + 1e-9f;
            float iou = inter / denom;                   // IEEE div, matches np
            bits = (bits & ~(1ull << jj)) | (((u64)(iou > 0.3f)) << jj);
        }
    }
    maskT[(size_t)w * N + i] = bits;                     // coalesced
}

// ========== Kernel 3: serial greedy pass (pipelined + DPP OR), maskT =========
// Best-measured variant (R5: 124.7 µs total). 64-row blocks; 2-block-deep
// pipe (col/s1/s2 + 4 column gathers); per-block suppression word via DPP
// row_shr/row_bcast OR-reduce (VALU, no LDS latency); in-block resolve via
// ballot symmetry on the diagonal word; kept at b-1/b-2 carried in registers
// (s1m / s2m_old). Serial-latency-bound at ~800 cy/block — structural
// alternatives (128-row steps, deeper pipes, lane-owned remv) all measured
// neutral or worse (R7-R12).
struct Pipe { u64 col, s1, s2, g0, g1, g2, g3; };

__device__ __forceinline__ unsigned or_dpp32(unsigned v) {
    v |= (unsigned)__builtin_amdgcn_update_dpp(0, (int)v, 0x111, 0xf, 0xf, true); // row_shr:1
    v |= (unsigned)__builtin_amdgcn_update_dpp(0, (int)v, 0x112, 0xf, 0xf, true); // row_shr:2
    v |= (unsigned)__builtin_amdgcn_update_dpp(0, (int)v, 0x114, 0xf, 0xf, true); // row_shr:4
    v |= (unsigned)__builtin_amdgcn_update_dpp(0, (int)v, 0x118, 0xf, 0xf, true); // row_shr:8
    v |= (unsigned)__builtin_amdgcn_update_dpp(0, (int)v, 0x142, 0xf, 0xf, true); // row_bcast:15
    v |= (unsigned)__builtin_amdgcn_update_dpp(0, (int)v, 0x143, 0xf, 0xf, true); // row_bcast:31
    return v;
}

__device__ __forceinline__ u64 wave_or64(u64 v) {
    unsigned lo = or_dpp32((unsigned)v);
    unsigned hi = or_dpp32((unsigned)(v >> 32));
    unsigned slo = (unsigned)__builtin_amdgcn_readlane((int)lo, 63);
    unsigned shi = (unsigned)__builtin_amdgcn_readlane((int)hi, 63);
    return ((u64)shi << 32) | (u64)slo;
}

__global__ __launch_bounds__(64)
void nms_kernel(const u64* __restrict__ maskT, const float* __restrict__ s_s,
                const int* __restrict__ order, const float* __restrict__ box,
                const int* __restrict__ nvalid_p, float* __restrict__ out) {
    const int lane = threadIdx.x;
    const int nv = *nvalid_p;
    const int nblk = (nv + 63) >> 6;
    __shared__ int kpos[MAX_OUT];
    int kcount = 0;
    u64 s1m = 0, s2m = 0, s2m_old = 0;

    Pipe A, B;
    A.col = A.s1 = A.s2 = A.g0 = A.g1 = A.g2 = A.g3 = 0;
    B.col = B.s1 = B.s2 = B.g0 = B.g1 = B.g2 = B.g3 = 0;
    if (nblk > 0) {
        A.col = maskT[lane];                                // w=0, rows 0..63
        if (nblk > 1) A.s1 = maskT[(size_t)1 * N + lane];
        if (nblk > 2) A.s2 = maskT[(size_t)2 * N + lane];
    }
    if (nblk > 1) {
        B.col = maskT[(size_t)1 * N + 64 + lane];           // w=1, rows 64..127
        if (nblk > 2) B.s1 = maskT[(size_t)2 * N + 64 + lane];
        if (nblk > 3) B.s2 = maskT[(size_t)3 * N + 64 + lane];
    }

    auto step = [&](int b, Pipe& P) -> bool {
        u64 col = P.col, s1v = P.s1, s2v = P.s2;
        u64 x = P.g0 | P.g1 | P.g2 | P.g3 | s1m | s2m_old;
        const int b2 = b + 2;
        P.col = P.s1 = P.s2 = P.g0 = P.g1 = P.g2 = P.g3 = 0;
        if (b2 < nblk) {
            const int row = (b2 << 6) + lane;
            P.col = maskT[(size_t)b2 * N + row];            // coalesced
            if (b2 + 1 < nblk) P.s1 = maskT[(size_t)(b2 + 1) * N + row];
            if (b2 + 2 < nblk) P.s2 = maskT[(size_t)(b2 + 2) * N + row];
            const int kc = kcount;
            const u64* colw = maskT + (size_t)b2 * N;       // 64KB word-column
            if (lane < kc)       P.g0 = colw[kpos[lane]];
            if (lane +  64 < kc) P.g1 = colw[kpos[lane +  64]];
            if (lane + 128 < kc) P.g2 = colw[kpos[lane + 128]];
            if (lane + 192 < kc) P.g3 = colw[kpos[lane + 192]];
        }
        u64 rw = wave_or64(x);
        const int base = b << 6;
        const int rem = nv - base;
        u64 validm = (rem >= 64) ? ~0ull : ((1ull << rem) - 1ull);
        u64 todo = validm & ~rw;
        u64 km = 0;
        while (todo) {
            int l = (int)__builtin_ctzll(todo);
            u64 row_l = __ballot(((col >> l) & 1ull) != 0);  // in-tile row via symmetry
            if (lane == 0) kpos[kcount] = base + l;
            km |= (1ull << l);
            kcount++;
            todo &= ~row_l;
            todo &= ~(1ull << l);
            if (kcount >= MAX_OUT) break;
        }
        u64 keepm = ((km >> lane) & 1ull) ? ~0ull : 0ull;
        s2m_old = s2m;
        s2m = s2v & keepm;
        s1m = s1v & keepm;
        return kcount < MAX_OUT;
    };

    bool run = true;
    for (int b = 0; run && b < nblk; b += 2) {
        run = step(b, A);
        if (run && b + 1 < nblk) run = step(b + 1, B);
    }

    __syncthreads();
    float* out_score = out;
    float* out_box   = out + MAX_OUT;
    float* out_valid = out + MAX_OUT + MAX_OUT * 16;
    const float4* box4 = (const float4*)box;
    float4* ob4 = (float4*)out_box;
    for (int t = lane; t < MAX_OUT; t += 64) {
        if (t < kcount) {
            int p = kpos[t];
            out_score[t] = s_s[p];
            out_valid[t] = 1.0f;
            int oi = order[p];
            #pragma unroll
            for (int q = 0; q < 4; ++q) ob4[t * 4 + q] = box4[oi * 4 + q];
        } else {
            out_score[t] = 0.0f;
            out_valid[t] = 0.0f;
            float4 z = make_float4(0.f, 0.f, 0.f, 0.f);
            #pragma unroll
            for (int q = 0; q < 4; ++q) ob4[t * 4 + q] = z;
        }
    }
}

extern "C" void kernel_launch(void* const* d_in, const int* in_sizes, int n_in,
                              void* d_out, int out_size, void* d_ws, size_t ws_size,
                              hipStream_t stream) {
    const float* score = (const float*)d_in[0];   // (8192,1) f32
    const float* box   = (const float*)d_in[1];   // (8192,16) f32
    char* ws = (char*)d_ws;
    u64*    maskT  = (u64*)ws;
    int*    order  = (int*)   (ws + MASK_BYTES);
    float*  s_s    = (float*) (ws + MASK_BYTES + 32768);
    float4* bbox   = (float4*)(ws + MASK_BYTES + 65536);
    float*  area   = (float*) (ws + MASK_BYTES + 65536 + 131072);
    int*    nvalid = (int*)   (ws + MASK_BYTES + 65536 + 131072 + 32768);

    rank_fused_kernel<<<256, 1024, 0, stream>>>(score, box, order, s_s, bbox, area, nvalid);
    mask_kernel<<<dim3(128, 32), 256, 0, stream>>>(bbox, area, nvalid, maskT);
    nms_kernel<<<1, 64, 0, stream>>>(maskT, s_s, order, box, nvalid, (float*)d_out);
}